// Round 12
// baseline (166.543 us; speedup 1.0000x reference)
//
#include <hip/hip_runtime.h>

typedef __attribute__((ext_vector_type(8))) short short8;
typedef __attribute__((ext_vector_type(4))) float f32x4;
typedef __attribute__((ext_vector_type(4))) unsigned int u32x4;

#define MFMA(a,b,c) __builtin_amdgcn_mfma_f32_16x16x32_bf16((a),(b),(c),0,0,0)

__device__ __forceinline__ unsigned short f2bf(float f){
    unsigned u = __float_as_uint(f);
    u += 0x7FFFu + ((u >> 16) & 1u);   // RNE
    return (unsigned short)(u >> 16);
}
__device__ __forceinline__ unsigned pack2(float lo, float hi){
    return (unsigned)f2bf(lo) | ((unsigned)f2bf(hi) << 16);
}

// d_out: 33,554,432 f32 = Re(out[b,j]) at flat b*4096 + j.
// y1 intermediate: packed bf16 complex u32 (re|im<<16) at u32 slot b*4096 + r*64 + l.
// d_ws (>=2 MiB): fragment-ready bf16 weights (same layouts as round 10).

// ---------------------------------------------------------------------------
__global__ __launch_bounds__(256) void k_prep(const float* __restrict__ w1,
                                              const float* __restrict__ w2,
                                              unsigned int* __restrict__ w1f,
                                              unsigned int* __restrict__ w2f){
    const int g = blockIdx.x * 256 + threadIdx.x;
    if (g < 65536) {
        const int lane = g & 63, mw = (g >> 6) & 3, kc = (g >> 8) & 1, c = (g >> 9) & 1, r = g >> 10;
        const int Lrow = lane >> 4, idx = lane & 15;
        const float* src = w1 + ((size_t)(r * 64 + mw * 16 + idx) * 64 + kc * 32 + Lrow * 8) * 2 + c;
        unsigned o[4];
        #pragma unroll
        for (int jp = 0; jp < 4; ++jp)
            o[jp] = pack2(src[jp * 4], src[jp * 4 + 2]);
        *(u32x4*)(w1f + (size_t)g * 4) = *(u32x4*)o;
    } else {
        const int h = g - 65536;
        const int lane = h & 63, mw = (h >> 6) & 3, kc = (h >> 8) & 3, l = h >> 10;
        const int Lrow = lane >> 4, idx = lane & 15;
        const float* src = w2 + ((size_t)(l * 64 + mw * 16 + idx) * 64 + kc * 16 + Lrow * 4) * 2;
        unsigned o[4];
        #pragma unroll
        for (int jp = 0; jp < 4; ++jp)
            o[jp] = pack2(src[jp * 2], -src[jp * 2 + 1]);   // (re, -im)
        *(u32x4*)(w2f + (size_t)h * 4) = *(u32x4*)o;
    }
}

// ---------------------------------------------------------------------------
// Stage 1 (fast): y1[b, r*64+l] = sum_p w1[r,l,p] * x[b, p*64+r]
// This round: (256,4) VGPR budget, 16-deep x-load MLP, 1-deep w prefetch
// pipeline. Output transpose through LDS + XCD pair swizzle as in r11.
// ---------------------------------------------------------------------------
__global__ __launch_bounds__(256, 4) void k_stage1f(const float* __restrict__ x,
                                                    const unsigned short* __restrict__ w1b,
                                                    unsigned int* __restrict__ y1){
    __shared__ unsigned int BF[8192];              // 32 KB
    const int tid = threadIdx.x;
    const int bid = blockIdx.x;
    // pair swizzle: (bt, rc=2k) at bid B, (bt, rc=2k+1) at B+8 (same XCD, adjacent)
    const int inner = (bid >> 3) & 1;
    const int pp = (bid >> 4) * 8 + (bid & 7);
    const int bt = pp >> 1, rc = (pp & 1) * 2 + inner;
    const int b0 = bt * 16, r0 = rc * 16;

    const int lane = tid & 63, mw = tid >> 6;
    const int Lrow = lane >> 4, idx = lane & 15;
    const unsigned short* wbase = w1b + mw * 512 + lane * 8;

    // ---- issue all 16 x loads up front (16-deep MLP vs HBM latency) ----
    const int pe = tid >> 3;
    const int rq = (tid >> 1) & 3;
    const int bh = tid & 1;
    const int kcs = pe >> 4, gg = (pe >> 2) & 3, jp = pe & 3;
    const float* src = x + (size_t)(b0 + bh * 8) * 4096 + (pe * 2) * 64 + r0 + rq * 4;
    f32x4 xv0[8], xv1[8];
    #pragma unroll
    for (int itr = 0; itr < 8; ++itr) {
        xv0[itr] = *(const f32x4*)(src + (size_t)itr * 4096);
        xv1[itr] = *(const f32x4*)(src + (size_t)itr * 4096 + 64);
    }

    // ---- prefetch w fragments for rr2=0 (independent of x staging) ----
    short8 wcur[2][2][2];                          // [kc][rp][c]
    #pragma unroll
    for (int kc = 0; kc < 2; ++kc)
        #pragma unroll
        for (int rp = 0; rp < 2; ++rp)
            #pragma unroll
            for (int c = 0; c < 2; ++c)
                wcur[kc][rp][c] = *(const short8*)(wbase + (size_t)(r0 + rp) * 8192 + kc * 2048 + c * 4096);

    // ---- pack + LDS write ----
    #pragma unroll
    for (int itr = 0; itr < 8; ++itr) {
        const int b = bh * 8 + itr;
        const int ROW = ((b ^ (b >> 3) ^ (gg << 1) ^ kcs ^ (rq << 2)) & 15) | (gg << 4);
        const int base = kcs * 256 + ROW * 4 + jp;
        #pragma unroll
        for (int m = 0; m < 4; ++m)
            BF[(rq * 4 + m) * 512 + base] = pack2(xv0[itr][m], xv1[itr][m]);
    }
    __syncthreads();

    u32x4 ou[8][2];                                // all outputs in regs

    #pragma unroll
    for (int rr2 = 0; rr2 < 8; ++rr2) {
        const int rA = rr2 * 2;
        short8 wnxt[2][2][2];
        if (rr2 < 7) {                             // prefetch next iteration's w
            #pragma unroll
            for (int kc = 0; kc < 2; ++kc)
                #pragma unroll
                for (int rp = 0; rp < 2; ++rp)
                    #pragma unroll
                    for (int c = 0; c < 2; ++c)
                        wnxt[kc][rp][c] = *(const short8*)(wbase + (size_t)(r0 + rA + 2 + rp) * 8192 + kc * 2048 + c * 4096);
        }
        f32x4 acc[2][2] = {};
        #pragma unroll
        for (int kc = 0; kc < 2; ++kc) {
            const int ROWr = ((idx ^ (idx >> 3) ^ (Lrow << 1) ^ kc ^ ((rr2 >> 1) << 2)) & 15) | (Lrow << 4);
            short8 bA = *(const short8*)&BF[(rA + 0) * 512 + kc * 256 + ROWr * 4];
            short8 bB = *(const short8*)&BF[(rA + 1) * 512 + kc * 256 + ROWr * 4];
            #pragma unroll
            for (int rp = 0; rp < 2; ++rp) {
                short8 bb = rp ? bB : bA;
                acc[rp][0] = MFMA(wcur[kc][rp][0], bb, acc[rp][0]);
                acc[rp][1] = MFMA(wcur[kc][rp][1], bb, acc[rp][1]);
            }
        }
        #pragma unroll
        for (int rp = 0; rp < 2; ++rp) {
            u32x4 ov;
            #pragma unroll
            for (int reg = 0; reg < 4; ++reg)
                ov[reg] = pack2(acc[rp][0][reg], acc[rp][1][reg]);   // re | im<<16
            ou[rr2][rp] = ov;
        }
        if (rr2 < 7) {
            #pragma unroll
            for (int kc = 0; kc < 2; ++kc)
                #pragma unroll
                for (int rp = 0; rp < 2; ++rp)
                    #pragma unroll
                    for (int c = 0; c < 2; ++c)
                        wcur[kc][rp][c] = wnxt[kc][rp][c];
        }
    }

    // ---- transpose through BF (dead now), two 32-KB halves ----
    const int l4 = mw * 16 + Lrow * 4;
    #pragma unroll
    for (int h = 0; h < 2; ++h) {
        __syncthreads();
        #pragma unroll
        for (int rr2 = h * 4; rr2 < h * 4 + 4; ++rr2) {
            #pragma unroll
            for (int rp = 0; rp < 2; ++rp) {
                const int rloc = rr2 * 2 + rp - h * 8;
                *(u32x4*)&BF[idx * 512 + rloc * 64 + ((l4 ^ ((idx & 7) << 2)))] = ou[rr2][rp];
            }
        }
        __syncthreads();
        const int b = tid >> 4, quad = tid & 15;
        #pragma unroll
        for (int rloc = 0; rloc < 8; ++rloc) {
            u32x4 v = *(const u32x4*)&BF[b * 512 + rloc * 64 + (((quad * 4) ^ ((b & 7) << 2)))];
            *(u32x4*)(y1 + (size_t)(b0 + b) * 4096 + (size_t)(r0 + h * 8 + rloc) * 64 + quad * 4) = v;
        }
    }
}

// ---------------------------------------------------------------------------
// Stage 2 (fast, real output only, in place over d_out) — unchanged from r11.
// ---------------------------------------------------------------------------
__global__ __launch_bounds__(256) void k_stage2f(const unsigned int* __restrict__ y1,
                                                 const unsigned short* __restrict__ w2b,
                                                 float* __restrict__ outf){
    __shared__ unsigned int Y[16384];              // 64 KB
    const int tid = threadIdx.x;
    const int bid = blockIdx.x;
    const int inner = (bid >> 3) & 1;
    const int pp = (bid >> 4) * 8 + (bid & 7);
    const int bt = pp >> 1, lc = (pp & 1) * 2 + inner;
    const int b0 = bt * 16, l0 = lc * 16;
    const int lane = tid & 63, mw = tid >> 6;
    const int Lrow = lane >> 4, idx = lane & 15;

    {   // ---- stage y1 l-slice -> LDS (all global reads precede the barrier) ----
        const int r_lo = lane >> 2, cg = lane & 3;
        const int r = mw * 16 + r_lo;
        const unsigned int* src = y1 + (size_t)b0 * 4096 + r * 64 + l0 + cg * 4;
        #pragma unroll
        for (int b = 0; b < 16; ++b) {
            u32x4 v = *(const u32x4*)(src + (size_t)b * 4096);
            const int rsw = r ^ (b << 2) ^ ((cg & 1) << 4);
            #pragma unroll
            for (int q = 0; q < 4; ++q)
                Y[(cg * 4 + q) * 1024 + b * 64 + rsw] = v[q];
        }
    }
    __syncthreads();

    const unsigned short* wbase = w2b + mw * 512 + lane * 8;
    float vRe[4][16];
    #pragma unroll
    for (int li = 0; li < 16; ++li) {
        const int l = l0 + li;
        const int g1 = ((li >> 2) & 1) << 4;
        f32x4 aRe = {};
        #pragma unroll
        for (int kc = 0; kc < 4; ++kc) {
            const int rb = kc * 16 + Lrow * 4;
            const int rsw = rb ^ (idx << 2) ^ g1;
            short8 bfrag = *(const short8*)&Y[li * 1024 + idx * 64 + rsw];
            short8 are   = *(const short8*)(wbase + (size_t)l * 8192 + kc * 2048);
            aRe = MFMA(are, bfrag, aRe);
        }
        #pragma unroll
        for (int reg = 0; reg < 4; ++reg)
            vRe[reg][li] = aRe[reg];
    }

    __syncthreads();
    float* Yf = (float*)Y;
    #pragma unroll
    for (int reg = 0; reg < 4; ++reg) {
        const int s = mw * 16 + Lrow * 4 + reg;
        #pragma unroll
        for (int q = 0; q < 4; ++q) {
            f32x4 v = { vRe[reg][q*4+0], vRe[reg][q*4+1], vRe[reg][q*4+2], vRe[reg][q*4+3] };
            *(f32x4*)&Yf[idx * 1024 + s * 16 + (((q ^ (idx & 3)) << 2))] = v;
        }
    }
    __syncthreads();

    {   // ---- coalesced store ----
        const int s2 = tid >> 2, c4 = tid & 3;
        #pragma unroll
        for (int i = 0; i < 16; ++i) {
            f32x4 v = *(const f32x4*)&Yf[i * 1024 + s2 * 16 + (((c4 ^ (i & 3)) << 2))];
            *(f32x4*)(outf + (size_t)(b0 + i) * 4096 + s2 * 64 + l0 + c4 * 4) = v;
        }
    }
}

// ===========================================================================
// Fallback path (round-9 verified kernels) — used only if ws_size < 2 MiB.
// ===========================================================================
__global__ __launch_bounds__(256) void k_stage1(const float* __restrict__ x,
                                                const float* __restrict__ w1,
                                                unsigned int* __restrict__ y1){
    __shared__ unsigned int BF[8192];
    const int tid = threadIdx.x;
    const int bt = blockIdx.x >> 2, rc = blockIdx.x & 3;
    const int b0 = bt * 16, r0 = rc * 16;
    {
        const int pe = tid >> 3;
        const int rq = (tid >> 1) & 3;
        const int bh = tid & 1;
        const int kc = pe >> 4, gg = (pe >> 2) & 3, jp = pe & 3;
        const float* src = x + (size_t)(b0 + bh * 8) * 4096 + (pe * 2) * 64 + r0 + rq * 4;
        #pragma unroll
        for (int itr = 0; itr < 8; ++itr) {
            f32x4 v0 = *(const f32x4*)(src + (size_t)itr * 4096);
            f32x4 v1 = *(const f32x4*)(src + (size_t)itr * 4096 + 64);
            const int b = bh * 8 + itr;
            const int ROW = ((b ^ (b >> 3) ^ (gg << 1) ^ kc ^ (rq << 2)) & 15) | (gg << 4);
            const int base = kc * 256 + ROW * 4 + jp;
            #pragma unroll
            for (int m = 0; m < 4; ++m)
                BF[(rq * 4 + m) * 512 + base] = pack2(v0[m], v1[m]);
        }
    }
    __syncthreads();
    const int lane = tid & 63, mw = tid >> 6;
    const int Lrow = lane >> 4, idx = lane & 15;
    #pragma unroll
    for (int rr2 = 0; rr2 < 8; ++rr2) {
        const int rA = rr2 * 2;
        f32x4 acc[2][2] = {};
        #pragma unroll
        for (int kc = 0; kc < 2; ++kc) {
            const int ROWr = ((idx ^ (idx >> 3) ^ (Lrow << 1) ^ kc ^ ((rr2 >> 1) << 2)) & 15) | (Lrow << 4);
            short8 bA = *(const short8*)&BF[(rA + 0) * 512 + kc * 256 + ROWr * 4];
            short8 bB = *(const short8*)&BF[(rA + 1) * 512 + kc * 256 + ROWr * 4];
            #pragma unroll
            for (int rp = 0; rp < 2; ++rp) {
                const int r = r0 + rA + rp;
                const float* wp = w1 + (((size_t)r * 64 + mw * 16 + idx) * 64 + kc * 32 + Lrow * 8) * 2;
                f32x4 q0 = *(const f32x4*)(wp);
                f32x4 q1 = *(const f32x4*)(wp + 4);
                f32x4 q2 = *(const f32x4*)(wp + 8);
                f32x4 q3 = *(const f32x4*)(wp + 12);
                short8 a0, a1;
                unsigned* p0 = (unsigned*)&a0; unsigned* p1 = (unsigned*)&a1;
                p0[0] = pack2(q0[0], q0[2]); p0[1] = pack2(q1[0], q1[2]);
                p0[2] = pack2(q2[0], q2[2]); p0[3] = pack2(q3[0], q3[2]);
                p1[0] = pack2(q0[1], q0[3]); p1[1] = pack2(q1[1], q1[3]);
                p1[2] = pack2(q2[1], q2[3]); p1[3] = pack2(q3[1], q3[3]);
                short8 bb = rp ? bB : bA;
                acc[rp][0] = MFMA(a0, bb, acc[rp][0]);
                acc[rp][1] = MFMA(a1, bb, acc[rp][1]);
            }
        }
        #pragma unroll
        for (int rp = 0; rp < 2; ++rp) {
            u32x4 ov;
            #pragma unroll
            for (int reg = 0; reg < 4; ++reg)
                ov[reg] = pack2(acc[rp][0][reg], acc[rp][1][reg]);
            *(u32x4*)(y1 + (size_t)(b0 + idx) * 4096 + (size_t)(r0 + rA + rp) * 64 + mw * 16 + Lrow * 4) = ov;
        }
    }
}

__global__ __launch_bounds__(256) void k_stage2(const unsigned int* __restrict__ y1,
                                                const float* __restrict__ w2,
                                                float* __restrict__ outf){
    __shared__ unsigned int Y[16384];
    const int tid = threadIdx.x;
    const int bt = blockIdx.x >> 2, lc = blockIdx.x & 3;
    const int b0 = bt * 16, l0 = lc * 16;
    const int lane = tid & 63, mw = tid >> 6;
    const int Lrow = lane >> 4, idx = lane & 15;
    {
        const int r_lo = lane >> 2, cg = lane & 3;
        const int r = mw * 16 + r_lo;
        const unsigned int* src = y1 + (size_t)b0 * 4096 + r * 64 + l0 + cg * 4;
        #pragma unroll
        for (int b = 0; b < 16; ++b) {
            u32x4 v = *(const u32x4*)(src + (size_t)b * 4096);
            const int rsw = r ^ (b << 2) ^ ((cg & 1) << 4);
            #pragma unroll
            for (int q = 0; q < 4; ++q)
                Y[(cg * 4 + q) * 1024 + b * 64 + rsw] = v[q];
        }
    }
    __syncthreads();
    float vRe[4][16];
    #pragma unroll
    for (int li = 0; li < 16; ++li) {
        const int l = l0 + li;
        const float* wp0 = w2 + ((size_t)l * 64 + mw * 16 + idx) * 128;
        const int g1 = ((li >> 2) & 1) << 4;
        f32x4 aRe = {};
        #pragma unroll
        for (int kc = 0; kc < 4; ++kc) {
            const int rb = kc * 16 + Lrow * 4;
            const int rsw = rb ^ (idx << 2) ^ g1;
            short8 bfrag = *(const short8*)&Y[li * 1024 + idx * 64 + rsw];
            const float* wp = wp0 + rb * 2;
            f32x4 u  = *(const f32x4*)wp;
            f32x4 vv = *(const f32x4*)(wp + 4);
            short8 are;
            unsigned* pr = (unsigned*)&are;
            pr[0] = pack2(u[0], -u[1]);   pr[1] = pack2(u[2], -u[3]);
            pr[2] = pack2(vv[0], -vv[1]); pr[3] = pack2(vv[2], -vv[3]);
            aRe = MFMA(are, bfrag, aRe);
        }
        #pragma unroll
        for (int reg = 0; reg < 4; ++reg)
            vRe[reg][li] = aRe[reg];
    }
    #pragma unroll
    for (int reg = 0; reg < 4; ++reg) {
        float* dst = outf + (size_t)(b0 + idx) * 4096 + (size_t)(mw * 16 + Lrow * 4 + reg) * 64 + l0;
        #pragma unroll
        for (int h = 0; h < 4; ++h) {
            f32x4 wv;
            wv[0] = vRe[reg][h*4+0]; wv[1] = vRe[reg][h*4+1];
            wv[2] = vRe[reg][h*4+2]; wv[3] = vRe[reg][h*4+3];
            *(f32x4*)(dst + h * 4) = wv;
        }
    }
}

extern "C" void kernel_launch(void* const* d_in, const int* in_sizes, int n_in,
                              void* d_out, int out_size, void* d_ws, size_t ws_size,
                              hipStream_t stream) {
    const float* x  = (const float*)d_in[0];
    const float* w1 = (const float*)d_in[1];
    const float* w2 = (const float*)d_in[2];
    unsigned int* y1 = (unsigned int*)d_out;
    float* outf = (float*)d_out;

    if (ws_size >= (size_t)2 * 1024 * 1024) {
        unsigned int* w1f = (unsigned int*)d_ws;           // 1 MiB
        unsigned int* w2f = w1f + 262144;                  // 1 MiB
        k_prep   <<<dim3(512),  dim3(256), 0, stream>>>(w1, w2, w1f, w2f);
        k_stage1f<<<dim3(2048), dim3(256), 0, stream>>>(x, (const unsigned short*)w1f, y1);
        k_stage2f<<<dim3(2048), dim3(256), 0, stream>>>(y1, (const unsigned short*)w2f, outf);
    } else {
        k_stage1<<<dim3(2048), dim3(256), 0, stream>>>(x, w1, y1);
        k_stage2<<<dim3(2048), dim3(256), 0, stream>>>(y1, w2, outf);
    }
}

// Round 13
// 138.802 us; speedup vs baseline: 1.1999x; 1.1999x over previous
//
#include <hip/hip_runtime.h>

typedef __attribute__((ext_vector_type(8))) short short8;
typedef __attribute__((ext_vector_type(4))) float f32x4;
typedef __attribute__((ext_vector_type(4))) unsigned int u32x4;

#define MFMA(a,b,c) __builtin_amdgcn_mfma_f32_16x16x32_bf16((a),(b),(c),0,0,0)

__device__ __forceinline__ unsigned short f2bf(float f){
    unsigned u = __float_as_uint(f);
    u += 0x7FFFu + ((u >> 16) & 1u);   // RNE
    return (unsigned short)(u >> 16);
}
__device__ __forceinline__ unsigned pack2(float lo, float hi){
    return (unsigned)f2bf(lo) | ((unsigned)f2bf(hi) << 16);
}

// d_out: 33,554,432 f32 = Re(out[b,j]) at flat b*4096 + j.
// y1 intermediate: packed bf16 complex u32 (re|im<<16) at u32 slot b*4096 + r*64 + l.
// d_ws (>=2 MiB): fragment-ready bf16 weights (layouts as round 10).

// ---------------------------------------------------------------------------
__global__ __launch_bounds__(256) void k_prep(const float* __restrict__ w1,
                                              const float* __restrict__ w2,
                                              unsigned int* __restrict__ w1f,
                                              unsigned int* __restrict__ w2f){
    const int g = blockIdx.x * 256 + threadIdx.x;
    if (g < 65536) {
        const int lane = g & 63, mw = (g >> 6) & 3, kc = (g >> 8) & 1, c = (g >> 9) & 1, r = g >> 10;
        const int Lrow = lane >> 4, idx = lane & 15;
        const float* src = w1 + ((size_t)(r * 64 + mw * 16 + idx) * 64 + kc * 32 + Lrow * 8) * 2 + c;
        unsigned o[4];
        #pragma unroll
        for (int jp = 0; jp < 4; ++jp)
            o[jp] = pack2(src[jp * 4], src[jp * 4 + 2]);
        *(u32x4*)(w1f + (size_t)g * 4) = *(u32x4*)o;
    } else {
        const int h = g - 65536;
        const int lane = h & 63, mw = (h >> 6) & 3, kc = (h >> 8) & 3, l = h >> 10;
        const int Lrow = lane >> 4, idx = lane & 15;
        const float* src = w2 + ((size_t)(l * 64 + mw * 16 + idx) * 64 + kc * 16 + Lrow * 4) * 2;
        unsigned o[4];
        #pragma unroll
        for (int jp = 0; jp < 4; ++jp)
            o[jp] = pack2(src[jp * 2], -src[jp * 2 + 1]);   // (re, -im)
        *(u32x4*)(w2f + (size_t)h * 4) = *(u32x4*)o;
    }
}

// ---------------------------------------------------------------------------
// Stage 1 (fast): y1[b, r*64+l] = sum_p w1[r,l,p] * x[b, p*64+r]
// r10 body (direct fragment stores — each (b,r) gets 256 B from 4 waves, no
// cross-block line split) + rc-pair XCD swizzle (paired blocks share x lines).
// ---------------------------------------------------------------------------
__global__ __launch_bounds__(256) void k_stage1f(const float* __restrict__ x,
                                                 const unsigned short* __restrict__ w1b,
                                                 unsigned int* __restrict__ y1){
    __shared__ unsigned int BF[8192];              // 32 KB
    const int tid = threadIdx.x;
    const int bid = blockIdx.x;
    // pair swizzle: (bt, rc=2k) at bid B, (bt, rc=2k+1) at B+8 (same XCD, adjacent)
    const int inner = (bid >> 3) & 1;
    const int pp = (bid >> 4) * 8 + (bid & 7);
    const int bt = pp >> 1, rc = (pp & 1) * 2 + inner;
    const int b0 = bt * 16, r0 = rc * 16;

    {   // ---- stage x tile -> LDS (u32-packed bf16 pairs, swizzled) ----
        const int pe = tid >> 3;
        const int rq = (tid >> 1) & 3;
        const int bh = tid & 1;
        const int kc = pe >> 4, gg = (pe >> 2) & 3, jp = pe & 3;
        const float* src = x + (size_t)(b0 + bh * 8) * 4096 + (pe * 2) * 64 + r0 + rq * 4;
        #pragma unroll
        for (int itr = 0; itr < 8; ++itr) {
            f32x4 v0 = *(const f32x4*)(src + (size_t)itr * 4096);
            f32x4 v1 = *(const f32x4*)(src + (size_t)itr * 4096 + 64);
            const int b = bh * 8 + itr;
            const int ROW = ((b ^ (b >> 3) ^ (gg << 1) ^ kc ^ (rq << 2)) & 15) | (gg << 4);
            const int base = kc * 256 + ROW * 4 + jp;
            #pragma unroll
            for (int m = 0; m < 4; ++m)
                BF[(rq * 4 + m) * 512 + base] = pack2(v0[m], v1[m]);
        }
    }
    __syncthreads();

    const int lane = tid & 63, mw = tid >> 6;
    const int Lrow = lane >> 4, idx = lane & 15;
    const unsigned short* wbase = w1b + mw * 512 + lane * 8;

    #pragma unroll
    for (int rr2 = 0; rr2 < 8; ++rr2) {
        const int rA = rr2 * 2;
        f32x4 acc[2][2] = {};
        #pragma unroll
        for (int kc = 0; kc < 2; ++kc) {
            const int ROWr = ((idx ^ (idx >> 3) ^ (Lrow << 1) ^ kc ^ ((rr2 >> 1) << 2)) & 15) | (Lrow << 4);
            short8 bA = *(const short8*)&BF[(rA + 0) * 512 + kc * 256 + ROWr * 4];
            short8 bB = *(const short8*)&BF[(rA + 1) * 512 + kc * 256 + ROWr * 4];
            #pragma unroll
            for (int rp = 0; rp < 2; ++rp) {
                const size_t wb = (size_t)(r0 + rA + rp) * 8192 + kc * 2048;
                short8 a0 = *(const short8*)(wbase + wb);          // re
                short8 a1 = *(const short8*)(wbase + wb + 4096);   // im
                short8 bb = rp ? bB : bA;
                acc[rp][0] = MFMA(a0, bb, acc[rp][0]);
                acc[rp][1] = MFMA(a1, bb, acc[rp][1]);
            }
        }
        #pragma unroll
        for (int rp = 0; rp < 2; ++rp) {
            u32x4 ov;
            #pragma unroll
            for (int reg = 0; reg < 4; ++reg)
                ov[reg] = pack2(acc[rp][0][reg], acc[rp][1][reg]);   // re | im<<16
            *(u32x4*)(y1 + (size_t)(b0 + idx) * 4096 + (size_t)(r0 + rA + rp) * 64 + mw * 16 + Lrow * 4) = ov;
        }
    }
}

// ---------------------------------------------------------------------------
// Stage 2 (fast, real output only, in place over d_out) — r11 version.
// ---------------------------------------------------------------------------
__global__ __launch_bounds__(256) void k_stage2f(const unsigned int* __restrict__ y1,
                                                 const unsigned short* __restrict__ w2b,
                                                 float* __restrict__ outf){
    __shared__ unsigned int Y[16384];              // 64 KB
    const int tid = threadIdx.x;
    const int bid = blockIdx.x;
    const int inner = (bid >> 3) & 1;
    const int pp = (bid >> 4) * 8 + (bid & 7);
    const int bt = pp >> 1, lc = (pp & 1) * 2 + inner;
    const int b0 = bt * 16, l0 = lc * 16;
    const int lane = tid & 63, mw = tid >> 6;
    const int Lrow = lane >> 4, idx = lane & 15;

    {   // ---- stage y1 l-slice -> LDS (all global reads precede the barrier) ----
        const int r_lo = lane >> 2, cg = lane & 3;
        const int r = mw * 16 + r_lo;
        const unsigned int* src = y1 + (size_t)b0 * 4096 + r * 64 + l0 + cg * 4;
        #pragma unroll
        for (int b = 0; b < 16; ++b) {
            u32x4 v = *(const u32x4*)(src + (size_t)b * 4096);
            const int rsw = r ^ (b << 2) ^ ((cg & 1) << 4);
            #pragma unroll
            for (int q = 0; q < 4; ++q)
                Y[(cg * 4 + q) * 1024 + b * 64 + rsw] = v[q];
        }
    }
    __syncthreads();

    const unsigned short* wbase = w2b + mw * 512 + lane * 8;
    float vRe[4][16];
    #pragma unroll
    for (int li = 0; li < 16; ++li) {
        const int l = l0 + li;
        const int g1 = ((li >> 2) & 1) << 4;
        f32x4 aRe = {};
        #pragma unroll
        for (int kc = 0; kc < 4; ++kc) {
            const int rb = kc * 16 + Lrow * 4;
            const int rsw = rb ^ (idx << 2) ^ g1;
            short8 bfrag = *(const short8*)&Y[li * 1024 + idx * 64 + rsw];
            short8 are   = *(const short8*)(wbase + (size_t)l * 8192 + kc * 2048);
            aRe = MFMA(are, bfrag, aRe);
        }
        #pragma unroll
        for (int reg = 0; reg < 4; ++reg)
            vRe[reg][li] = aRe[reg];
    }

    __syncthreads();
    float* Yf = (float*)Y;
    #pragma unroll
    for (int reg = 0; reg < 4; ++reg) {
        const int s = mw * 16 + Lrow * 4 + reg;
        #pragma unroll
        for (int q = 0; q < 4; ++q) {
            f32x4 v = { vRe[reg][q*4+0], vRe[reg][q*4+1], vRe[reg][q*4+2], vRe[reg][q*4+3] };
            *(f32x4*)&Yf[idx * 1024 + s * 16 + (((q ^ (idx & 3)) << 2))] = v;
        }
    }
    __syncthreads();

    {   // ---- coalesced store ----
        const int s2 = tid >> 2, c4 = tid & 3;
        #pragma unroll
        for (int i = 0; i < 16; ++i) {
            f32x4 v = *(const f32x4*)&Yf[i * 1024 + s2 * 16 + (((c4 ^ (i & 3)) << 2))];
            *(f32x4*)(outf + (size_t)(b0 + i) * 4096 + s2 * 64 + l0 + c4 * 4) = v;
        }
    }
}

// ===========================================================================
// Fallback path (round-9 verified kernels) — used only if ws_size < 2 MiB.
// ===========================================================================
__global__ __launch_bounds__(256) void k_stage1(const float* __restrict__ x,
                                                const float* __restrict__ w1,
                                                unsigned int* __restrict__ y1){
    __shared__ unsigned int BF[8192];
    const int tid = threadIdx.x;
    const int bt = blockIdx.x >> 2, rc = blockIdx.x & 3;
    const int b0 = bt * 16, r0 = rc * 16;
    {
        const int pe = tid >> 3;
        const int rq = (tid >> 1) & 3;
        const int bh = tid & 1;
        const int kc = pe >> 4, gg = (pe >> 2) & 3, jp = pe & 3;
        const float* src = x + (size_t)(b0 + bh * 8) * 4096 + (pe * 2) * 64 + r0 + rq * 4;
        #pragma unroll
        for (int itr = 0; itr < 8; ++itr) {
            f32x4 v0 = *(const f32x4*)(src + (size_t)itr * 4096);
            f32x4 v1 = *(const f32x4*)(src + (size_t)itr * 4096 + 64);
            const int b = bh * 8 + itr;
            const int ROW = ((b ^ (b >> 3) ^ (gg << 1) ^ kc ^ (rq << 2)) & 15) | (gg << 4);
            const int base = kc * 256 + ROW * 4 + jp;
            #pragma unroll
            for (int m = 0; m < 4; ++m)
                BF[(rq * 4 + m) * 512 + base] = pack2(v0[m], v1[m]);
        }
    }
    __syncthreads();
    const int lane = tid & 63, mw = tid >> 6;
    const int Lrow = lane >> 4, idx = lane & 15;
    #pragma unroll
    for (int rr2 = 0; rr2 < 8; ++rr2) {
        const int rA = rr2 * 2;
        f32x4 acc[2][2] = {};
        #pragma unroll
        for (int kc = 0; kc < 2; ++kc) {
            const int ROWr = ((idx ^ (idx >> 3) ^ (Lrow << 1) ^ kc ^ ((rr2 >> 1) << 2)) & 15) | (Lrow << 4);
            short8 bA = *(const short8*)&BF[(rA + 0) * 512 + kc * 256 + ROWr * 4];
            short8 bB = *(const short8*)&BF[(rA + 1) * 512 + kc * 256 + ROWr * 4];
            #pragma unroll
            for (int rp = 0; rp < 2; ++rp) {
                const int r = r0 + rA + rp;
                const float* wp = w1 + (((size_t)r * 64 + mw * 16 + idx) * 64 + kc * 32 + Lrow * 8) * 2;
                f32x4 q0 = *(const f32x4*)(wp);
                f32x4 q1 = *(const f32x4*)(wp + 4);
                f32x4 q2 = *(const f32x4*)(wp + 8);
                f32x4 q3 = *(const f32x4*)(wp + 12);
                short8 a0, a1;
                unsigned* p0 = (unsigned*)&a0; unsigned* p1 = (unsigned*)&a1;
                p0[0] = pack2(q0[0], q0[2]); p0[1] = pack2(q1[0], q1[2]);
                p0[2] = pack2(q2[0], q2[2]); p0[3] = pack2(q3[0], q3[2]);
                p1[0] = pack2(q0[1], q0[3]); p1[1] = pack2(q1[1], q1[3]);
                p1[2] = pack2(q2[1], q2[3]); p1[3] = pack2(q3[1], q3[3]);
                short8 bb = rp ? bB : bA;
                acc[rp][0] = MFMA(a0, bb, acc[rp][0]);
                acc[rp][1] = MFMA(a1, bb, acc[rp][1]);
            }
        }
        #pragma unroll
        for (int rp = 0; rp < 2; ++rp) {
            u32x4 ov;
            #pragma unroll
            for (int reg = 0; reg < 4; ++reg)
                ov[reg] = pack2(acc[rp][0][reg], acc[rp][1][reg]);
            *(u32x4*)(y1 + (size_t)(b0 + idx) * 4096 + (size_t)(r0 + rA + rp) * 64 + mw * 16 + Lrow * 4) = ov;
        }
    }
}

__global__ __launch_bounds__(256) void k_stage2(const unsigned int* __restrict__ y1,
                                                const float* __restrict__ w2,
                                                float* __restrict__ outf){
    __shared__ unsigned int Y[16384];
    const int tid = threadIdx.x;
    const int bt = blockIdx.x >> 2, lc = blockIdx.x & 3;
    const int b0 = bt * 16, l0 = lc * 16;
    const int lane = tid & 63, mw = tid >> 6;
    const int Lrow = lane >> 4, idx = lane & 15;
    {
        const int r_lo = lane >> 2, cg = lane & 3;
        const int r = mw * 16 + r_lo;
        const unsigned int* src = y1 + (size_t)b0 * 4096 + r * 64 + l0 + cg * 4;
        #pragma unroll
        for (int b = 0; b < 16; ++b) {
            u32x4 v = *(const u32x4*)(src + (size_t)b * 4096);
            const int rsw = r ^ (b << 2) ^ ((cg & 1) << 4);
            #pragma unroll
            for (int q = 0; q < 4; ++q)
                Y[(cg * 4 + q) * 1024 + b * 64 + rsw] = v[q];
        }
    }
    __syncthreads();
    float vRe[4][16];
    #pragma unroll
    for (int li = 0; li < 16; ++li) {
        const int l = l0 + li;
        const float* wp0 = w2 + ((size_t)l * 64 + mw * 16 + idx) * 128;
        const int g1 = ((li >> 2) & 1) << 4;
        f32x4 aRe = {};
        #pragma unroll
        for (int kc = 0; kc < 4; ++kc) {
            const int rb = kc * 16 + Lrow * 4;
            const int rsw = rb ^ (idx << 2) ^ g1;
            short8 bfrag = *(const short8*)&Y[li * 1024 + idx * 64 + rsw];
            const float* wp = wp0 + rb * 2;
            f32x4 u  = *(const f32x4*)wp;
            f32x4 vv = *(const f32x4*)(wp + 4);
            short8 are;
            unsigned* pr = (unsigned*)&are;
            pr[0] = pack2(u[0], -u[1]);   pr[1] = pack2(u[2], -u[3]);
            pr[2] = pack2(vv[0], -vv[1]); pr[3] = pack2(vv[2], -vv[3]);
            aRe = MFMA(are, bfrag, aRe);
        }
        #pragma unroll
        for (int reg = 0; reg < 4; ++reg)
            vRe[reg][li] = aRe[reg];
    }
    #pragma unroll
    for (int reg = 0; reg < 4; ++reg) {
        float* dst = outf + (size_t)(b0 + idx) * 4096 + (size_t)(mw * 16 + Lrow * 4 + reg) * 64 + l0;
        #pragma unroll
        for (int h = 0; h < 4; ++h) {
            f32x4 wv;
            wv[0] = vRe[reg][h*4+0]; wv[1] = vRe[reg][h*4+1];
            wv[2] = vRe[reg][h*4+2]; wv[3] = vRe[reg][h*4+3];
            *(f32x4*)(dst + h * 4) = wv;
        }
    }
}

extern "C" void kernel_launch(void* const* d_in, const int* in_sizes, int n_in,
                              void* d_out, int out_size, void* d_ws, size_t ws_size,
                              hipStream_t stream) {
    const float* x  = (const float*)d_in[0];
    const float* w1 = (const float*)d_in[1];
    const float* w2 = (const float*)d_in[2];
    unsigned int* y1 = (unsigned int*)d_out;
    float* outf = (float*)d_out;

    if (ws_size >= (size_t)2 * 1024 * 1024) {
        unsigned int* w1f = (unsigned int*)d_ws;           // 1 MiB
        unsigned int* w2f = w1f + 262144;                  // 1 MiB
        k_prep   <<<dim3(512),  dim3(256), 0, stream>>>(w1, w2, w1f, w2f);
        k_stage1f<<<dim3(2048), dim3(256), 0, stream>>>(x, (const unsigned short*)w1f, y1);
        k_stage2f<<<dim3(2048), dim3(256), 0, stream>>>(y1, (const unsigned short*)w2f, outf);
    } else {
        k_stage1<<<dim3(2048), dim3(256), 0, stream>>>(x, w1, y1);
        k_stage2<<<dim3(2048), dim3(256), 0, stream>>>(y1, w2, outf);
    }
}